// Round 1
// baseline (19.052 us; speedup 1.0000x reference)
//
#include <hip/hip_runtime.h>

// Locally-connected 3D conv (unshared weights), fp32.
// x:      (2, 24, 24, 24, 8)          = 221184 floats
// kernel: (10648, 216, 8)             = 18,399,744 floats (73.6 MB) -- the traffic
// bias:   (22, 22, 22, 8)             = 42592 floats
// out:    (2, 22, 22, 22, 8)          = 170368 floats
//
// One wave per output location p. kernel[p] is 432 contiguous float4s,
// streamed coalesced by the wave. Even lanes accumulate f0..3, odd lanes
// f4..7 (a float4 never straddles a k since F=8). Butterfly-reduce over
// same-parity lanes, lanes 0/1 write the 2x8 outputs.

constexpr int P_TOT = 22 * 22 * 22;   // 10648
constexpr int KTOT  = 216;            // 3*3*3*8
constexpr int NF    = 8;
constexpr int XB    = 24 * 24 * 24 * 8;  // 110592, batch stride of x
constexpr int NV4   = KTOT * NF / 4;  // 432 float4 per p

__global__ __launch_bounds__(256) void lc3d_kernel(
    const float* __restrict__ x,
    const float* __restrict__ kern,
    const float* __restrict__ bias,
    float* __restrict__ out)
{
    __shared__ int offs[KTOT];
    const int tid = threadIdx.x;
    if (tid < KTOT) {
        const int k  = tid;
        const int di = k / 72;
        const int r  = k - di * 72;
        const int dj = r / 24;
        const int r2 = r - dj * 24;
        const int dk = r2 >> 3;
        const int c  = r2 & 7;
        offs[k] = di * 4608 + dj * 192 + dk * 8 + c;   // x strides: d=4608,h=192,w=8,c=1
    }
    __syncthreads();

    const int wave = tid >> 6;
    const int lane = tid & 63;
    const int p    = blockIdx.x * 4 + wave;            // grid sized exactly: 10648/4 waves

    const int oz  = p % 22;
    const int t   = p / 22;
    const int oc  = t % 22;
    const int orr = t / 22;
    const int xbase = orr * 4608 + oc * 192 + oz * 8;  // b=0 patch origin

    const float4* kp4 = reinterpret_cast<const float4*>(kern) + (size_t)p * NV4;

    float4 a0 = make_float4(0.f, 0.f, 0.f, 0.f);       // batch 0
    float4 a1 = make_float4(0.f, 0.f, 0.f, 0.f);       // batch 1

    auto body = [&](int j) {
        const float4 kv = kp4[j];
        const int k  = j >> 1;                          // 8 floats per k -> float4 j covers one k
        const int xo = xbase + offs[k];
        const float x0 = x[xo];
        const float x1 = x[xo + XB];
        a0.x = fmaf(x0, kv.x, a0.x);
        a0.y = fmaf(x0, kv.y, a0.y);
        a0.z = fmaf(x0, kv.z, a0.z);
        a0.w = fmaf(x0, kv.w, a0.w);
        a1.x = fmaf(x1, kv.x, a1.x);
        a1.y = fmaf(x1, kv.y, a1.y);
        a1.z = fmaf(x1, kv.z, a1.z);
        a1.w = fmaf(x1, kv.w, a1.w);
    };

    #pragma unroll
    for (int i = 0; i < 6; ++i) body(lane + 64 * i);   // 384 float4s
    if (lane < 48) body(lane + 384);                   // tail: 432 total

    // Butterfly reduce across the 32 lanes of the same parity class.
    #pragma unroll
    for (int m = 2; m <= 32; m <<= 1) {
        a0.x += __shfl_xor(a0.x, m, 64);
        a0.y += __shfl_xor(a0.y, m, 64);
        a0.z += __shfl_xor(a0.z, m, 64);
        a0.w += __shfl_xor(a0.w, m, 64);
        a1.x += __shfl_xor(a1.x, m, 64);
        a1.y += __shfl_xor(a1.y, m, 64);
        a1.z += __shfl_xor(a1.z, m, 64);
        a1.w += __shfl_xor(a1.w, m, 64);
    }

    if (lane < 2) {
        const int fb = lane * 4;                        // lane0 -> f0..3, lane1 -> f4..7
        const float4 bv = *reinterpret_cast<const float4*>(bias + (size_t)p * NF + fb);
        float4 o0, o1;
        o0.x = a0.x + bv.x;  o0.y = a0.y + bv.y;  o0.z = a0.z + bv.z;  o0.w = a0.w + bv.w;
        o1.x = a1.x + bv.x;  o1.y = a1.y + bv.y;  o1.z = a1.z + bv.z;  o1.w = a1.w + bv.w;
        *reinterpret_cast<float4*>(out + (size_t)p * NF + fb) = o0;
        *reinterpret_cast<float4*>(out + (size_t)P_TOT * NF + (size_t)p * NF + fb) = o1;
    }
}

extern "C" void kernel_launch(void* const* d_in, const int* in_sizes, int n_in,
                              void* d_out, int out_size, void* d_ws, size_t ws_size,
                              hipStream_t stream) {
    const float* x    = (const float*)d_in[0];
    const float* kern = (const float*)d_in[1];
    const float* bias = (const float*)d_in[2];
    float* out        = (float*)d_out;

    const int blocks = P_TOT / 4;   // 2662, exact (4 waves of 64 per block)
    lc3d_kernel<<<blocks, 256, 0, stream>>>(x, kern, bias, out);
}

// Round 2
// 18.856 us; speedup vs baseline: 1.0104x; 1.0104x over previous
//
#include <hip/hip_runtime.h>

// Locally-connected 3D conv (unshared weights), fp32.
// x:      (2, 24, 24, 24, 8)   = 221184 floats (884 KB, cache-resident)
// kernel: (10648, 216, 8)      = 73.6 MB  -- the streaming traffic
// bias:   (22, 22, 22, 8)
// out:    (2, 22, 22, 22, 8)
//
// One wave per output location p. Wave stages its 2x216-float x-patch into
// LDS (k-linear layout) with coalesced float4 loads, then streams kernel[p]
// as 432 contiguous float4s (1 KB/instr). Inner body: 1 dwordx4 + 2
// conflict-free ds_read_b32 + 8 FMA. Butterfly-reduce same-parity lanes,
// lanes 0/1 write the 2x8 outputs.

constexpr int P_TOT = 22 * 22 * 22;      // 10648
constexpr int KTOT  = 216;               // 3*3*3*8
constexpr int XB    = 24 * 24 * 24 * 8;  // batch stride of x
constexpr int NV4   = KTOT * 8 / 4;      // 432 float4 per p

__global__ __launch_bounds__(256) void lc3d_kernel(
    const float* __restrict__ x,
    const float* __restrict__ kern,
    const float* __restrict__ bias,
    float* __restrict__ out)
{
    // Per-wave patch scratch, k-linear: xl[wave][b*216 + k], k = ((di*3+dj)*3+dk)*8+c
    __shared__ float xl[4][2 * KTOT];    // 6912 B

    const int tid  = threadIdx.x;
    const int wave = tid >> 6;
    const int lane = tid & 63;
    const int p    = blockIdx.x * 4 + wave;   // grid exact: 10648 = 2662*4

    const int oz  = p % 22;
    const int t   = p / 22;
    const int oc  = t % 22;
    const int orr = t / 22;
    const int xbase = orr * 4608 + oc * 192 + oz * 8;  // x strides: d=4608,h=192,w=8,c=1

    float* xw = xl[wave];

    // ---- stage both patches (b=0,1) into LDS, k-linear ----
    // 108 float4s: t4 -> seg = t4/6 (0..17), wi = t4%6
    // seg -> b = seg/9, s = seg%9 = di*3+dj; each segment = 24 contiguous floats of x
    #pragma unroll
    for (int r = 0; r < 2; ++r) {
        const int t4 = lane + r * 64;
        if (t4 < 108) {
            const int seg = t4 / 6;
            const int wi  = t4 - seg * 6;
            const int b   = seg / 9;
            const int s   = seg - b * 9;
            const int di  = s / 3;
            const int dj  = s - di * 3;
            const float4 v = *reinterpret_cast<const float4*>(
                x + (size_t)b * XB + xbase + di * 4608 + dj * 192 + wi * 4);
            *reinterpret_cast<float4*>(xw + seg * 24 + wi * 4) = v;
        }
    }
    // No __syncthreads: each wave reads only its own LDS slice; in-wave
    // ds_write -> ds_read ordering is handled by lgkmcnt waits.

    const float4* kp4 = reinterpret_cast<const float4*>(kern) + (size_t)p * NV4;
    const int k0 = lane >> 1;             // float4 j covers k = j>>1 (F=8: two f4 per k)

    float4 a0 = make_float4(0.f, 0.f, 0.f, 0.f);   // batch 0 (even lanes f0-3, odd f4-7)
    float4 a1 = make_float4(0.f, 0.f, 0.f, 0.f);   // batch 1

    auto body = [&](int j, int k) {
        const float4 kv = kp4[j];
        const float x0 = xw[k];
        const float x1 = xw[KTOT + k];
        a0.x = fmaf(x0, kv.x, a0.x);
        a0.y = fmaf(x0, kv.y, a0.y);
        a0.z = fmaf(x0, kv.z, a0.z);
        a0.w = fmaf(x0, kv.w, a0.w);
        a1.x = fmaf(x1, kv.x, a1.x);
        a1.y = fmaf(x1, kv.y, a1.y);
        a1.z = fmaf(x1, kv.z, a1.z);
        a1.w = fmaf(x1, kv.w, a1.w);
    };

    #pragma unroll
    for (int i = 0; i < 6; ++i) body(lane + 64 * i, k0 + 32 * i);  // 384 float4s
    if (lane < 48) body(lane + 384, k0 + 192);                     // tail -> 432

    // Butterfly reduce across the 32 lanes of the same parity class.
    #pragma unroll
    for (int m = 2; m <= 32; m <<= 1) {
        a0.x += __shfl_xor(a0.x, m, 64);
        a0.y += __shfl_xor(a0.y, m, 64);
        a0.z += __shfl_xor(a0.z, m, 64);
        a0.w += __shfl_xor(a0.w, m, 64);
        a1.x += __shfl_xor(a1.x, m, 64);
        a1.y += __shfl_xor(a1.y, m, 64);
        a1.z += __shfl_xor(a1.z, m, 64);
        a1.w += __shfl_xor(a1.w, m, 64);
    }

    if (lane < 2) {
        const int fb = lane * 4;          // lane0 -> f0..3, lane1 -> f4..7
        const float4 bv = *reinterpret_cast<const float4*>(bias + (size_t)p * 8 + fb);
        float4 o0, o1;
        o0.x = a0.x + bv.x;  o0.y = a0.y + bv.y;  o0.z = a0.z + bv.z;  o0.w = a0.w + bv.w;
        o1.x = a1.x + bv.x;  o1.y = a1.y + bv.y;  o1.z = a1.z + bv.z;  o1.w = a1.w + bv.w;
        *reinterpret_cast<float4*>(out + (size_t)p * 8 + fb) = o0;
        *reinterpret_cast<float4*>(out + (size_t)P_TOT * 8 + (size_t)p * 8 + fb) = o1;
    }
}

extern "C" void kernel_launch(void* const* d_in, const int* in_sizes, int n_in,
                              void* d_out, int out_size, void* d_ws, size_t ws_size,
                              hipStream_t stream) {
    const float* x    = (const float*)d_in[0];
    const float* kern = (const float*)d_in[1];
    const float* bias = (const float*)d_in[2];
    float* out        = (float*)d_out;

    lc3d_kernel<<<P_TOT / 4, 256, 0, stream>>>(x, kern, bias, out);
}